// Round 16
// baseline (77.273 us; speedup 1.0000x reference)
//
#include <hip/hip_runtime.h>
#include <hip/hip_fp16.h>

#define IMG_H 1024
#define IMG_W 1024
#define NIMG  16
#define RAD   5
#define KW    11
#define TX    64              // tile width (cols)
#define STRIP 128             // tile height (rows per block)
#define ASTEP 16              // h-blur rows per A phase
#define BSTEP 32              // output rows per B phase
#define HBROWS (STRIP + 2*RAD)   // 138 h-blurred rows per strip
#define RING  48              // LDS ring rows
#define PADW  68              // halfs per ring row (136 B)
#define NQ    4               // ring quantities: x, y, xx+yy, xy
#define NPIX  (NIMG * IMG_H * IMG_W)

// Gaussian(sigma=1.5, 11 taps), normalized fp32 — matches reference window.
__device__ __forceinline__ float gw(int k) {
    constexpr float G[KW] = {
        0.00102838f, 0.00759876f, 0.03600077f, 0.10936070f, 0.21300554f,
        0.26601173f,
        0.21300554f, 0.10936070f, 0.03600077f, 0.00759876f, 0.00102838f};
    return G[k];
}

__device__ __forceinline__ unsigned h2u(__half2 v) {
    union { __half2 h; unsigned u; } c; c.h = v; return c.u;
}
__device__ __forceinline__ __half2 u2h(unsigned v) {
    union { unsigned u; __half2 h; } c; c.u = v; return c.h;
}
// halfs (w[idx], w[idx+1]) from packed word array; odd idx = v_alignbit.
// idx is compile-time under full unroll (rule #20 safe).
__device__ __forceinline__ __half2 hsel(const unsigned* hw, int idx) {
    unsigned r;
    if (idx & 1) r = (hw[idx >> 1] >> 16) | (hw[(idx >> 1) + 1] << 16);
    else         r = hw[idx >> 1];
    return u2h(r);
}

// R13 body (proven: 79.6 us, VGPR 60, no spill) + 4-quantity algebra:
// SSIM needs only blur(x), blur(y), blur(xx+yy), blur(xy) —
// sigma1_sq+sigma2_sq = blur(xx+yy) - mu1^2 - mu2^2. 20% less LDS
// capacity/traffic/fma; ring 26,112 B -> 6 blocks/CU.
__global__ __launch_bounds__(256, 8) void ssim_strip_kernel(
        const float* __restrict__ img1, const float* __restrict__ img2,
        float* __restrict__ partial, int atomic_mode) {
    __shared__ __align__(16) __half hb[NQ][RING][PADW];
    __shared__ float wsum[4];

    const int t = threadIdx.x;
    const int tile_x = blockIdx.x * TX;
    const int tile_y = blockIdx.y * STRIP;
    const size_t img_off = (size_t)blockIdx.z * (IMG_H * IMG_W);
    const float* p1 = img1 + img_off;
    const float* p2 = img2 + img_off;

    const bool x_ok = (tile_x >= 8) && (tile_x + 72 <= IMG_W);

    // Phase A step a: h-blur halo rows h = 16a+(t>>4) into ring slot h%48.
    // One 4-col unit per thread; window kept as packed fp16 words.
    auto phaseA = [&](int a) {
        const int tr = t >> 4;
        const int g4 = t & 15;
        const int h = ASTEP * a + tr;
        if (h >= HBROWS) return;
        int rr = h;
        if (rr >= 96) rr -= 96;
        else if (rr >= RING) rr -= RING;
        const int gr = tile_y + h - RAD;
        const int gc0 = tile_x + g4 * 4 - 8;
        const bool row_ok = (tile_y + ASTEP * a - RAD >= 0) &&
                            (tile_y + ASTEP * a + ASTEP - 1 - RAD < IMG_H);
        unsigned hwx[10], hwy[10];
        if (x_ok && row_ok) {
            const size_t base = (size_t)gr * IMG_W + gc0;
#pragma unroll
            for (int w = 0; w < 5; ++w) {
                const float4 xa = *reinterpret_cast<const float4*>(p1 + base + 4 * w);
                const float4 ya = *reinterpret_cast<const float4*>(p2 + base + 4 * w);
                hwx[2 * w]     = h2u(__floats2half2_rn(xa.x, xa.y));
                hwx[2 * w + 1] = h2u(__floats2half2_rn(xa.z, xa.w));
                hwy[2 * w]     = h2u(__floats2half2_rn(ya.x, ya.y));
                hwy[2 * w + 1] = h2u(__floats2half2_rn(ya.z, ya.w));
            }
        } else {
            const bool rowok = ((unsigned)gr < (unsigned)IMG_H);
            const float* row1 = p1 + (size_t)gr * IMG_W;
            const float* row2 = p2 + (size_t)gr * IMG_W;
#pragma unroll
            for (int w = 0; w < 5; ++w) {
                const int gc = gc0 + 4 * w;
                float4 xa = make_float4(0.f, 0.f, 0.f, 0.f);
                float4 ya = make_float4(0.f, 0.f, 0.f, 0.f);
                if (rowok) {
                    if (gc >= 0 && gc <= IMG_W - 4) {
                        xa = *reinterpret_cast<const float4*>(row1 + gc);
                        ya = *reinterpret_cast<const float4*>(row2 + gc);
                    } else if (gc > -4 && gc < IMG_W) {
                        float* ex = &xa.x;
                        float* ey = &ya.x;
#pragma unroll
                        for (int j = 0; j < 4; ++j) {
                            int g = gc + j;
                            if ((unsigned)g < (unsigned)IMG_W) {
                                ex[j] = row1[g];
                                ey[j] = row2[g];
                            }
                        }
                    }
                }
                hwx[2 * w]     = h2u(__floats2half2_rn(xa.x, xa.y));
                hwx[2 * w + 1] = h2u(__floats2half2_rn(xa.z, xa.w));
                hwy[2 * w]     = h2u(__floats2half2_rn(ya.x, ya.y));
                hwy[2 * w + 1] = h2u(__floats2half2_rn(ya.z, ya.w));
            }
        }
        // packed-fp16 h-blur: 4 cols = 2 half2 lanes per quantity.
        // A2 accumulates g*(xx+yy) directly (two fma, one accumulator).
        __half2 A0[2], A1[2], A2[2], A3[2];
#pragma unroll
        for (int p = 0; p < 2; ++p)
            A0[p] = A1[p] = A2[p] = A3[p] = u2h(0u);
#pragma unroll
        for (int k = 0; k < KW; ++k) {
            const __half2 g2 = __float2half2_rn(gw(k));
#pragma unroll
            for (int p = 0; p < 2; ++p) {
                const int idx = 2 * p + 3 + k;
                const __half2 X = hsel(hwx, idx);
                const __half2 Y = hsel(hwy, idx);
                A0[p] = __hfma2(g2, X, A0[p]);
                A1[p] = __hfma2(g2, Y, A1[p]);
                const __half2 gx = __hmul2(g2, X);
                const __half2 gy = __hmul2(g2, Y);
                A2[p] = __hfma2(gx, X, A2[p]);
                A2[p] = __hfma2(gy, Y, A2[p]);
                A3[p] = __hfma2(gx, Y, A3[p]);
            }
        }
        *reinterpret_cast<uint2*>(&hb[0][rr][g4 * 4]) = make_uint2(h2u(A0[0]), h2u(A0[1]));
        *reinterpret_cast<uint2*>(&hb[1][rr][g4 * 4]) = make_uint2(h2u(A1[0]), h2u(A1[1]));
        *reinterpret_cast<uint2*>(&hb[2][rr][g4 * 4]) = make_uint2(h2u(A2[0]), h2u(A2[1]));
        *reinterpret_cast<uint2*>(&hb[3][rr][g4 * 4]) = make_uint2(h2u(A3[0]), h2u(A3[1]));
    };

    float lsum = 0.f;

    // Phase B step s: v-blur + SSIM for output rows 32s..32s+31.
    // thread: 4 cols (slot = t&15) x 2 rows (r2 = (t>>4)*2).
    auto phaseB = [&](int s) {
        __half2 gh2[KW];
#pragma unroll
        for (int k = 0; k < KW; ++k) gh2[k] = __float2half2_rn(gw(k));

        const int rbase = (BSTEP * s) % RING;   // 0,32,16,0
        const int slot = t & 15;
        const int r2 = (t >> 4) * 2;
        __half2 acc[NQ][2][2];
#pragma unroll
        for (int q = 0; q < NQ; ++q)
#pragma unroll
            for (int rl = 0; rl < 2; ++rl)
#pragma unroll
                for (int cp = 0; cp < 2; ++cp)
                    acc[q][rl][cp] = u2h(0u);

#pragma unroll
        for (int q = 0; q < NQ; ++q) {
#pragma unroll
            for (int k = 0; k < KW + 1; ++k) {
                int r = rbase + r2 + k;     // <= 32+30+11 = 73
                if (r >= RING) r -= RING;
                const uint2 rv =
                    *reinterpret_cast<const uint2*>(&hb[q][r][slot * 4]);
                __half2 h0 = u2h(rv.x);
                __half2 h1 = u2h(rv.y);
                if (k < KW) {
                    acc[q][0][0] = __hfma2(gh2[k], h0, acc[q][0][0]);
                    acc[q][0][1] = __hfma2(gh2[k], h1, acc[q][0][1]);
                }
                if (k > 0) {
                    acc[q][1][0] = __hfma2(gh2[k - 1], h0, acc[q][1][0]);
                    acc[q][1][1] = __hfma2(gh2[k - 1], h1, acc[q][1][1]);
                }
            }
        }

        const float C1 = 0.0001f;
        const float C2 = 0.0009f;
#pragma unroll
        for (int rl = 0; rl < 2; ++rl) {
#pragma unroll
            for (int cp = 0; cp < 2; ++cp) {
                float2 m1p = __half22float2(acc[0][rl][cp]);
                float2 m2p = __half22float2(acc[1][rl][cp]);
                float2 Sp  = __half22float2(acc[2][rl][cp]);   // blur(xx+yy)
                float2 Pp  = __half22float2(acc[3][rl][cp]);   // blur(xy)
#pragma unroll
                for (int e = 0; e < 2; ++e) {
                    float m1 = e ? m1p.y : m1p.x;
                    float m2 = e ? m2p.y : m2p.x;
                    float S  = e ? Sp.y  : Sp.x;
                    float P  = e ? Pp.y  : Pp.x;
                    float m1s = m1 * m1;
                    float m2s = m2 * m2;
                    float m12 = m1 * m2;
                    float sigsum = S - m1s - m2s;
                    float sig12  = P - m12;
                    float num = (2.f * m12 + C1) * (2.f * sig12 + C2);
                    float den = (m1s + m2s + C1) * (sigsum + C2);
                    lsum = fmaf(num, __builtin_amdgcn_rcpf(den), lsum);
                }
            }
        }
    };

    // R13's compact rolled schedule (best measured). Ring safety as
    // verified in R9/R11 (unchanged: same RING/ASTEP/BSTEP).
#pragma unroll 1
    for (int a = 0; a < 9; ++a) {
        phaseA(a);
        __syncthreads();
        if (a >= 2 && ((a & 1) == 0)) {
            phaseB((a - 2) >> 1);
            __syncthreads();
        }
    }

    // ---- block reduction ----
#pragma unroll
    for (int off = 32; off > 0; off >>= 1)
        lsum += __shfl_down(lsum, off, 64);
    if ((t & 63) == 0) wsum[t >> 6] = lsum;
    __syncthreads();
    if (t == 0) {
        float s = wsum[0] + wsum[1] + wsum[2] + wsum[3];
        if (atomic_mode) {
            atomicAdd(partial, s);
        } else {
            int bid = (blockIdx.z * gridDim.y + blockIdx.y) * gridDim.x + blockIdx.x;
            partial[bid] = s;
        }
    }
}

__global__ __launch_bounds__(256) void ssim_reduce_kernel(
        const float* __restrict__ partial, int n, float* __restrict__ out) {
    float s = 0.f;
    for (int i = threadIdx.x; i < n; i += 256) s += partial[i];
#pragma unroll
    for (int off = 32; off > 0; off >>= 1)
        s += __shfl_down(s, off, 64);
    __shared__ float ws[4];
    if ((threadIdx.x & 63) == 0) ws[threadIdx.x >> 6] = s;
    __syncthreads();
    if (threadIdx.x == 0) {
        float tot = ws[0] + ws[1] + ws[2] + ws[3];
        out[0] = 1.f - tot / (float)NPIX;
    }
}

extern "C" void kernel_launch(void* const* d_in, const int* in_sizes, int n_in,
                              void* d_out, int out_size, void* d_ws, size_t ws_size,
                              hipStream_t stream) {
    const float* img1 = (const float*)d_in[0];
    const float* img2 = (const float*)d_in[1];
    float* out = (float*)d_out;
    float* partial = (float*)d_ws;

    dim3 grid(IMG_W / TX, IMG_H / STRIP, NIMG);   // 16 x 8 x 16 = 2048 blocks
    const int nblocks = (IMG_W / TX) * (IMG_H / STRIP) * NIMG;
    const size_t needed = (size_t)nblocks * sizeof(float);

    if (ws_size >= needed) {
        ssim_strip_kernel<<<grid, 256, 0, stream>>>(img1, img2, partial, 0);
        ssim_reduce_kernel<<<1, 256, 0, stream>>>(partial, nblocks, out);
    } else {
        hipMemsetAsync(d_ws, 0, sizeof(float), stream);
        ssim_strip_kernel<<<grid, 256, 0, stream>>>(img1, img2, partial, 1);
        ssim_reduce_kernel<<<1, 256, 0, stream>>>(partial, 1, out);
    }
}

// Round 17
// 67.670 us; speedup vs baseline: 1.1419x; 1.1419x over previous
//
#include <hip/hip_runtime.h>
#include <hip/hip_fp16.h>

#define IMG_H 1024
#define IMG_W 1024
#define NIMG  16
#define RAD   5
#define KW    11
#define TX    64              // block tile width (cols); 16 per wave
#define WTX   16              // cols per wave
#define STRIP 128             // tile height (rows per block)
#define ASTEP 16              // h-blur rows per A step
#define BSTEP 32              // output rows per B step
#define HBROWS (STRIP + 2*RAD)   // 138 h-blurred rows per strip
#define RING  48              // ring rows per wave
#define WPAD  20              // halfs per ring row per wave (16 + 4 pad)
#define NQ    4               // ring quantities: x, y, xx+yy, xy
#define NPIX  (NIMG * IMG_H * IMG_W)

// Gaussian(sigma=1.5, 11 taps), normalized fp32 — matches reference window.
__device__ __forceinline__ float gw(int k) {
    constexpr float G[KW] = {
        0.00102838f, 0.00759876f, 0.03600077f, 0.10936070f, 0.21300554f,
        0.26601173f,
        0.21300554f, 0.10936070f, 0.03600077f, 0.00759876f, 0.00102838f};
    return G[k];
}

__device__ __forceinline__ unsigned h2u(__half2 v) {
    union { __half2 h; unsigned u; } c; c.h = v; return c.u;
}
__device__ __forceinline__ __half2 u2h(unsigned v) {
    union { unsigned u; __half2 h; } c; c.u = v; return c.h;
}
// halfs (w[idx], w[idx+1]) from packed word array; odd idx = v_alignbit.
__device__ __forceinline__ __half2 hsel(const unsigned* hw, int idx) {
    unsigned r;
    if (idx & 1) r = (hw[idx >> 1] >> 16) | (hw[(idx >> 1) + 1] << 16);
    else         r = hw[idx >> 1];
    return u2h(r);
}

// WAVE-PRIVATE rings: each wave owns a 16-col strip and its own ring —
// A-writes and B-reads never cross waves, so program order (+ compiler
// lgkmcnt) replaces ALL main-loop __syncthreads (R16's 13-barrier lockstep
// pinned VALUBusy at ~48% across 5 structurally different rounds).
// Per-thread work identical to R16; h-blur windows were per-thread anyway.
__global__ __launch_bounds__(256, 8) void ssim_strip_kernel(
        const float* __restrict__ img1, const float* __restrict__ img2,
        float* __restrict__ partial, int atomic_mode) {
    __shared__ __align__(16) __half hb[4][NQ][RING][WPAD];   // 30,720 B
    __shared__ float wsum[4];

    const int t = threadIdx.x;
    const int wid = t >> 6;
    const int lane = t & 63;
    const int tile_y = blockIdx.y * STRIP;
    const int wx = blockIdx.x * TX + wid * WTX;   // wave's first output col
    const size_t img_off = (size_t)blockIdx.z * (IMG_H * IMG_W);
    const float* p1 = img1 + img_off;
    const float* p2 = img2 + img_off;

    const bool x_ok = (wx >= 8) && (wx + 24 <= IMG_W);

    // Phase A step a: h-blur halo rows h = 16a + (lane>>2) into the wave's
    // ring slot h%48, col group g4 = lane&3 (4 cols each).
    auto phaseA = [&](int a) {
        const int lr = lane >> 2;
        const int g4 = lane & 3;
        const int h = ASTEP * a + lr;
        if (h >= HBROWS) return;
        int rr = h;
        if (rr >= 96) rr -= 96;
        else if (rr >= RING) rr -= RING;
        const int gr = tile_y + h - RAD;
        const int gc0 = wx + g4 * 4 - 8;
        const bool row_ok = (tile_y + ASTEP * a - RAD >= 0) &&
                            (tile_y + ASTEP * a + ASTEP - 1 - RAD < IMG_H);
        unsigned hwx[10], hwy[10];
        if (x_ok && row_ok) {
            const size_t base = (size_t)gr * IMG_W + gc0;
#pragma unroll
            for (int w = 0; w < 5; ++w) {
                const float4 xa = *reinterpret_cast<const float4*>(p1 + base + 4 * w);
                const float4 ya = *reinterpret_cast<const float4*>(p2 + base + 4 * w);
                hwx[2 * w]     = h2u(__floats2half2_rn(xa.x, xa.y));
                hwx[2 * w + 1] = h2u(__floats2half2_rn(xa.z, xa.w));
                hwy[2 * w]     = h2u(__floats2half2_rn(ya.x, ya.y));
                hwy[2 * w + 1] = h2u(__floats2half2_rn(ya.z, ya.w));
            }
        } else {
            const bool rowok = ((unsigned)gr < (unsigned)IMG_H);
            const float* row1 = p1 + (size_t)gr * IMG_W;
            const float* row2 = p2 + (size_t)gr * IMG_W;
#pragma unroll
            for (int w = 0; w < 5; ++w) {
                const int gc = gc0 + 4 * w;
                float4 xa = make_float4(0.f, 0.f, 0.f, 0.f);
                float4 ya = make_float4(0.f, 0.f, 0.f, 0.f);
                if (rowok) {
                    if (gc >= 0 && gc <= IMG_W - 4) {
                        xa = *reinterpret_cast<const float4*>(row1 + gc);
                        ya = *reinterpret_cast<const float4*>(row2 + gc);
                    } else if (gc > -4 && gc < IMG_W) {
                        float* ex = &xa.x;
                        float* ey = &ya.x;
#pragma unroll
                        for (int j = 0; j < 4; ++j) {
                            int g = gc + j;
                            if ((unsigned)g < (unsigned)IMG_W) {
                                ex[j] = row1[g];
                                ey[j] = row2[g];
                            }
                        }
                    }
                }
                hwx[2 * w]     = h2u(__floats2half2_rn(xa.x, xa.y));
                hwx[2 * w + 1] = h2u(__floats2half2_rn(xa.z, xa.w));
                hwy[2 * w]     = h2u(__floats2half2_rn(ya.x, ya.y));
                hwy[2 * w + 1] = h2u(__floats2half2_rn(ya.z, ya.w));
            }
        }
        __half2 A0[2], A1[2], A2[2], A3[2];
#pragma unroll
        for (int p = 0; p < 2; ++p)
            A0[p] = A1[p] = A2[p] = A3[p] = u2h(0u);
#pragma unroll
        for (int k = 0; k < KW; ++k) {
            const __half2 g2 = __float2half2_rn(gw(k));
#pragma unroll
            for (int p = 0; p < 2; ++p) {
                const int idx = 2 * p + 3 + k;
                const __half2 X = hsel(hwx, idx);
                const __half2 Y = hsel(hwy, idx);
                A0[p] = __hfma2(g2, X, A0[p]);
                A1[p] = __hfma2(g2, Y, A1[p]);
                const __half2 gx = __hmul2(g2, X);
                const __half2 gy = __hmul2(g2, Y);
                A2[p] = __hfma2(gx, X, A2[p]);
                A2[p] = __hfma2(gy, Y, A2[p]);
                A3[p] = __hfma2(gx, Y, A3[p]);
            }
        }
        *reinterpret_cast<uint2*>(&hb[wid][0][rr][g4 * 4]) = make_uint2(h2u(A0[0]), h2u(A0[1]));
        *reinterpret_cast<uint2*>(&hb[wid][1][rr][g4 * 4]) = make_uint2(h2u(A1[0]), h2u(A1[1]));
        *reinterpret_cast<uint2*>(&hb[wid][2][rr][g4 * 4]) = make_uint2(h2u(A2[0]), h2u(A2[1]));
        *reinterpret_cast<uint2*>(&hb[wid][3][rr][g4 * 4]) = make_uint2(h2u(A3[0]), h2u(A3[1]));
    };

    float lsum = 0.f;

    // Phase B step s: v-blur + SSIM for output rows 32s..32s+31.
    // lane: 4 cols (slot = lane&3) x 2 rows (r2 = (lane>>2)*2).
    auto phaseB = [&](int s) {
        __half2 gh2[KW];
#pragma unroll
        for (int k = 0; k < KW; ++k) gh2[k] = __float2half2_rn(gw(k));

        const int rbase = (BSTEP * s) % RING;   // 0,32,16,0
        const int slot = lane & 3;
        const int r2 = (lane >> 2) * 2;
        __half2 acc[NQ][2][2];
#pragma unroll
        for (int q = 0; q < NQ; ++q)
#pragma unroll
            for (int rl = 0; rl < 2; ++rl)
#pragma unroll
                for (int cp = 0; cp < 2; ++cp)
                    acc[q][rl][cp] = u2h(0u);

#pragma unroll
        for (int q = 0; q < NQ; ++q) {
#pragma unroll
            for (int k = 0; k < KW + 1; ++k) {
                int r = rbase + r2 + k;
                if (r >= RING) r -= RING;
                const uint2 rv =
                    *reinterpret_cast<const uint2*>(&hb[wid][q][r][slot * 4]);
                __half2 h0 = u2h(rv.x);
                __half2 h1 = u2h(rv.y);
                if (k < KW) {
                    acc[q][0][0] = __hfma2(gh2[k], h0, acc[q][0][0]);
                    acc[q][0][1] = __hfma2(gh2[k], h1, acc[q][0][1]);
                }
                if (k > 0) {
                    acc[q][1][0] = __hfma2(gh2[k - 1], h0, acc[q][1][0]);
                    acc[q][1][1] = __hfma2(gh2[k - 1], h1, acc[q][1][1]);
                }
            }
        }

        const float C1 = 0.0001f;
        const float C2 = 0.0009f;
#pragma unroll
        for (int rl = 0; rl < 2; ++rl) {
#pragma unroll
            for (int cp = 0; cp < 2; ++cp) {
                float2 m1p = __half22float2(acc[0][rl][cp]);
                float2 m2p = __half22float2(acc[1][rl][cp]);
                float2 Sp  = __half22float2(acc[2][rl][cp]);   // blur(xx+yy)
                float2 Pp  = __half22float2(acc[3][rl][cp]);   // blur(xy)
#pragma unroll
                for (int e = 0; e < 2; ++e) {
                    float m1 = e ? m1p.y : m1p.x;
                    float m2 = e ? m2p.y : m2p.x;
                    float S  = e ? Sp.y  : Sp.x;
                    float P  = e ? Pp.y  : Pp.x;
                    float m1s = m1 * m1;
                    float m2s = m2 * m2;
                    float m12 = m1 * m2;
                    float sigsum = S - m1s - m2s;
                    float sig12  = P - m12;
                    float num = (2.f * m12 + C1) * (2.f * sig12 + C2);
                    float den = (m1s + m2s + C1) * (sigsum + C2);
                    lsum = fmaf(num, __builtin_amdgcn_rcpf(den), lsum);
                }
            }
        }
    };

    // Barrier-free per-wave schedule (ring safety identical to R9/R16:
    // same RING/ASTEP/BSTEP stepping, now enforced by wave program order).
#pragma unroll 1
    for (int a = 0; a < 9; ++a) {
        phaseA(a);
        if (a >= 2 && ((a & 1) == 0)) {
            phaseB((a - 2) >> 1);
        }
    }

    // ---- block reduction (single barrier of the kernel) ----
#pragma unroll
    for (int off = 32; off > 0; off >>= 1)
        lsum += __shfl_down(lsum, off, 64);
    if (lane == 0) wsum[wid] = lsum;
    __syncthreads();
    if (t == 0) {
        float s = wsum[0] + wsum[1] + wsum[2] + wsum[3];
        if (atomic_mode) {
            atomicAdd(partial, s);
        } else {
            int bid = (blockIdx.z * gridDim.y + blockIdx.y) * gridDim.x + blockIdx.x;
            partial[bid] = s;
        }
    }
}

__global__ __launch_bounds__(256) void ssim_reduce_kernel(
        const float* __restrict__ partial, int n, float* __restrict__ out) {
    float s = 0.f;
    for (int i = threadIdx.x; i < n; i += 256) s += partial[i];
#pragma unroll
    for (int off = 32; off > 0; off >>= 1)
        s += __shfl_down(s, off, 64);
    __shared__ float ws[4];
    if ((threadIdx.x & 63) == 0) ws[threadIdx.x >> 6] = s;
    __syncthreads();
    if (threadIdx.x == 0) {
        float tot = ws[0] + ws[1] + ws[2] + ws[3];
        out[0] = 1.f - tot / (float)NPIX;
    }
}

extern "C" void kernel_launch(void* const* d_in, const int* in_sizes, int n_in,
                              void* d_out, int out_size, void* d_ws, size_t ws_size,
                              hipStream_t stream) {
    const float* img1 = (const float*)d_in[0];
    const float* img2 = (const float*)d_in[1];
    float* out = (float*)d_out;
    float* partial = (float*)d_ws;

    dim3 grid(IMG_W / TX, IMG_H / STRIP, NIMG);   // 16 x 8 x 16 = 2048 blocks
    const int nblocks = (IMG_W / TX) * (IMG_H / STRIP) * NIMG;
    const size_t needed = (size_t)nblocks * sizeof(float);

    if (ws_size >= needed) {
        ssim_strip_kernel<<<grid, 256, 0, stream>>>(img1, img2, partial, 0);
        ssim_reduce_kernel<<<1, 256, 0, stream>>>(partial, nblocks, out);
    } else {
        hipMemsetAsync(d_ws, 0, sizeof(float), stream);
        ssim_strip_kernel<<<grid, 256, 0, stream>>>(img1, img2, partial, 1);
        ssim_reduce_kernel<<<1, 256, 0, stream>>>(partial, 1, out);
    }
}